// Round 9
// baseline (68.025 us; speedup 1.0000x reference)
//
#include <hip/hip_runtime.h>

// pAUC loss, single-dispatch, REDUNDANT-SELECT, round 14 (DPP scans):
//   bce(i,j) = -log(clip(sigmoid(pos_i - neg_j), 1e-6, 1-1e-6))
//   out = sum_i topk_j(bce, K=512) / (N_pos * N_neg)
// bce monotone in neg_j => row top-K = K largest negatives. Every block
// runs the T-only select locally (R13 structure, verified).
//
// R14 vs R13: the scans were the LDS-pipe hogs, not the histograms.
// Per-thread per-scan: 16 wsuf reads + 7 shfl (ds_bpermute = LDS pipe!)
// = ~52K of the block's ~78K LDS ops. Replaced with:
//  - DPP wave64 inclusive prefix (row_shr:1/2/4/8 + row_bcast:15/31 via
//    __builtin_amdgcn_update_dpp, old=0 so masked/invalid lanes add 0)
//    -> VALU pipe, zero LDS.
//  - wtot[16] read as 4x uint4 broadcast (4 LDS ops, was 16).
//  - s_next = suf - c (algebraic; the shfl_down(suf,1) was never needed).
//  - final float reductions: same DPP sequence, lane 63 holds wave sum.
// One suffix_pick helper serves scan1, scan2, and the fallback passes
// (same 2-barrier shape as R13 -> control flow unchanged).

#define TOPK 512
#define BT   1024
#define GRID 256
#define EPT  16                  // BT * EPT = 16384 >= n_neg
#define NHIST 8                  // pass-0 histogram copies (wave pairs)
#define CAP   1024               // max sub-bin candidates for rank path
#define POS_LDS 1024
#define BCE_LO 1.0000005e-6f     // -log(1-1e-6)
#define BCE_HI 13.8155106f       // -log(1e-6)

__device__ __forceinline__ float decode_key(unsigned int ky) {
    unsigned int u = (ky >> 31) ? (ky ^ 0x80000000u) : (ky ^ 0xFFFFFFFFu);
    return __uint_as_float(u);
}

// ---- wave64 inclusive prefix sum on the VALU pipe (classic gfx9 DPP) ----
// old=0 in every step => lanes not written by row_mask (or invalid source
// lanes) contribute +0, so bound_ctrl ambiguity is harmless.
__device__ __forceinline__ unsigned wave_iprefix_u32(unsigned x) {
    x += (unsigned)__builtin_amdgcn_update_dpp(0, (int)x, 0x111, 0xf, 0xf, true);  // row_shr:1
    x += (unsigned)__builtin_amdgcn_update_dpp(0, (int)x, 0x112, 0xf, 0xf, true);  // row_shr:2
    x += (unsigned)__builtin_amdgcn_update_dpp(0, (int)x, 0x114, 0xf, 0xf, true);  // row_shr:4
    x += (unsigned)__builtin_amdgcn_update_dpp(0, (int)x, 0x118, 0xf, 0xf, true);  // row_shr:8
    x += (unsigned)__builtin_amdgcn_update_dpp(0, (int)x, 0x142, 0xa, 0xf, false); // row_bcast:15
    x += (unsigned)__builtin_amdgcn_update_dpp(0, (int)x, 0x143, 0xc, 0xf, false); // row_bcast:31
    return x;
}
__device__ __forceinline__ float wave_iprefix_f32(float x) {
    // same movement on bit patterns; +0.0f (bit pattern 0) is the identity
    x += __uint_as_float((unsigned)__builtin_amdgcn_update_dpp(
            0, (int)__float_as_uint(x), 0x111, 0xf, 0xf, true));
    x += __uint_as_float((unsigned)__builtin_amdgcn_update_dpp(
            0, (int)__float_as_uint(x), 0x112, 0xf, 0xf, true));
    x += __uint_as_float((unsigned)__builtin_amdgcn_update_dpp(
            0, (int)__float_as_uint(x), 0x114, 0xf, 0xf, true));
    x += __uint_as_float((unsigned)__builtin_amdgcn_update_dpp(
            0, (int)__float_as_uint(x), 0x118, 0xf, 0xf, true));
    x += __uint_as_float((unsigned)__builtin_amdgcn_update_dpp(
            0, (int)__float_as_uint(x), 0x142, 0xa, 0xf, false));
    x += __uint_as_float((unsigned)__builtin_amdgcn_update_dpp(
            0, (int)__float_as_uint(x), 0x143, 0xc, 0xf, false));
    return x;
}

// Block-wide crossing-bin pick: c = this thread's bin count (bin id = tid;
// threads beyond the bin range must pass c = 0, which can never satisfy
// the crossing test). Writes bc[0]=digit, bc[1]=kk-in-bin, bc[2]=bin count.
// Contains 2 __syncthreads (same shape as the R13 scan) — call uniformly.
__device__ __forceinline__ void suffix_pick(
    unsigned c, unsigned kk, int tid, int lane, int wv,
    unsigned* wtot, unsigned* bc_digit, unsigned* bc_kk, unsigned* bc_cd) {
    unsigned inc = wave_iprefix_u32(c);
    unsigned wtw = (unsigned)__builtin_amdgcn_readlane((int)inc, 63); // wave total
    if (lane == 63) wtot[wv] = inc;
    __syncthreads();
    uint4 a = ((const uint4*)wtot)[0];
    uint4 b = ((const uint4*)wtot)[1];
    uint4 d = ((const uint4*)wtot)[2];
    uint4 e = ((const uint4*)wtot)[3];
    unsigned wsuf = 0u;                 // sum of wtot[w] for w > wv
    wsuf += (wv < 1 ) ? a.y : 0u;
    wsuf += (wv < 2 ) ? a.z : 0u;
    wsuf += (wv < 3 ) ? a.w : 0u;
    wsuf += (wv < 4 ) ? b.x : 0u;
    wsuf += (wv < 5 ) ? b.y : 0u;
    wsuf += (wv < 6 ) ? b.z : 0u;
    wsuf += (wv < 7 ) ? b.w : 0u;
    wsuf += (wv < 8 ) ? d.x : 0u;
    wsuf += (wv < 9 ) ? d.y : 0u;
    wsuf += (wv < 10) ? d.z : 0u;
    wsuf += (wv < 11) ? d.w : 0u;
    wsuf += (wv < 12) ? e.x : 0u;
    wsuf += (wv < 13) ? e.y : 0u;
    wsuf += (wv < 14) ? e.z : 0u;
    wsuf += (wv < 15) ? e.w : 0u;
    unsigned suf = wsuf + wtw - (inc - c);   // suffix count incl. own bin
    unsigned snx = suf - c;                  // = suf of bin tid+1
    if (suf >= kk && snx < kk) {
        *bc_digit = (unsigned)tid;
        *bc_kk    = kk - snx;
        *bc_cd    = c;
    }
    __syncthreads();
}

__global__ __launch_bounds__(BT, 4) void pauc_fused_kernel(
    const float* __restrict__ neg, int n_neg,
    const float* __restrict__ pos, int n_pos,
    float* __restrict__ out, float inv_denom, int k,
    float* __restrict__ partials, unsigned int* __restrict__ done) {
    const int tid  = threadIdx.x;
    const int lane = tid & 63;
    const int wv   = tid >> 6;

    // hist: pass-0 copies (32 KB); dead after scan1/fallback -> reused as
    // 16 wave-private compaction buffers of 512 floats each.
    __shared__ __align__(16) unsigned int hist[NHIST * 1024];
    __shared__ __align__(16) unsigned int hist2[1024];        // level-2 bins
    __shared__ __align__(16) unsigned int cand2[CAP + 4];     // sub-bin cands
    __shared__ float        s_pos[POS_LDS];
    __shared__ __align__(16) unsigned int wtot[16];
    __shared__ unsigned int bc_digit, bc_kk, bc_cd;
    __shared__ unsigned int out_cd2;
    __shared__ unsigned int sh_T, sh_g2;
    __shared__ float        s_red[BT / 64];

    const int rows_pb = (n_pos + GRID - 1) / GRID;      // 32 in harness
    const bool pos_in_lds = rows_pb <= POS_LDS;

    // -------- issue pos prefetch FIRST (latency hides under select) --------
    float pv0 = 0.0f;
    const int prow = blockIdx.x * rows_pb + tid;
    const bool pv0_v = pos_in_lds && (tid < rows_pb) && (prow < n_pos);
    if (pv0_v) pv0 = pos[prow];

    // ---------------- load all keys (every block, redundant) ----------------
    unsigned int keys[EPT];
    if (n_neg == BT * EPT) {                // harness case: float4 loads
        const float4* n4 = (const float4*)neg;
        #pragma unroll
        for (int t = 0; t < EPT / 4; ++t) {
            float4 v = n4[t * BT + tid];
            unsigned int u0 = __float_as_uint(v.x), u1 = __float_as_uint(v.y);
            unsigned int u2 = __float_as_uint(v.z), u3 = __float_as_uint(v.w);
            keys[4*t+0] = u0 ^ (0x80000000u | (unsigned)((int)u0 >> 31));
            keys[4*t+1] = u1 ^ (0x80000000u | (unsigned)((int)u1 >> 31));
            keys[4*t+2] = u2 ^ (0x80000000u | (unsigned)((int)u2 >> 31));
            keys[4*t+3] = u3 ^ (0x80000000u | (unsigned)((int)u3 >> 31));
        }
    } else {
        #pragma unroll
        for (int t = 0; t < EPT; ++t) {
            int i = t * BT + tid;
            unsigned int key = 0u;          // pad = smallest key
            if (i < n_neg) {
                unsigned int u = __float_as_uint(neg[i]);
                key = u ^ (0x80000000u | (unsigned)((int)u >> 31));
            }
            keys[t] = key;
        }
    }

    // zero histograms + counters (cand2 zeroed so rank pads read 0)
    #pragma unroll
    for (int i = 0; i < NHIST; ++i) hist[(i << 10) + tid] = 0u;
    hist2[tid] = 0u;
    cand2[tid] = 0u;
    if (tid < 4) cand2[CAP + tid] = 0u;
    if (tid == 0) out_cd2 = 0u;
    if (pos_in_lds && tid < rows_pb) s_pos[tid] = pv0_v ? pv0 : 0.0f;
    __syncthreads();                                            // B1

    // ---------------- pass 0: privatized 10-bit histogram (copy/wave-pair) --
    {
        unsigned int* h = &hist[(unsigned)(wv >> 1) << 10];
        #pragma unroll
        for (int t = 0; t < EPT; ++t)
            atomicAdd(&h[keys[t] >> 22], 1u);
    }
    __syncthreads();                                            // B2

    // merge 8 copies (stride-1024: conflict-free) + DPP crossing pick
    unsigned int c = 0u;
    #pragma unroll
    for (int i = 0; i < NHIST; ++i) c += hist[(i << 10) + tid];
    const unsigned int k0 = (unsigned)k;
    suffix_pick(c, k0, tid, lane, wv, wtot, &bc_digit, &bc_kk, &bc_cd);

    const unsigned int B  = bc_digit;
    const unsigned int kkv = bc_kk;
    const unsigned int cd  = bc_cd;

    unsigned int Tkey  = 0u;
    unsigned int n_tie = 0u;
    if (kkv == cd) {
        // whole level-1 bin selected: T = bin lower boundary - 1, no ties.
        // (B==0 with kkv==cd impossible for k < total-counted keys.)
        Tkey = B ? ((B << 22) - 1u) : 0u;
    } else {
        // ---- level-2 histogram (bits 12..21) over bin==B keys (registers) --
        #pragma unroll
        for (int t = 0; t < EPT; ++t) {
            unsigned int ky = keys[t];
            if ((ky >> 22) == B)
                atomicAdd(&hist2[(ky >> 12) & 1023u], 1u);
        }
        __syncthreads();                                        // B5
        unsigned int c2 = hist2[tid];
        suffix_pick(c2, kkv, tid, lane, wv, wtot, &bc_digit, &bc_kk, &bc_cd);
        const unsigned int B2   = bc_digit;
        const unsigned int kkv2 = bc_kk;
        const unsigned int cd2  = bc_cd;
        if (kkv2 == cd2) {
            // whole sub-bin selected: T just below sub-bin, no ties.
            // (B,B2)==(0,0) here would imply kkv==cd, handled above.
            Tkey = ((B << 22) | (B2 << 12)) - 1u;
        } else if (cd2 <= CAP) {
            // compact sub-bin candidates from register keys (expected 1-3)
            #pragma unroll
            for (int t = 0; t < EPT; ++t) {
                unsigned int ky = keys[t];
                bool e2 = ((ky >> 22) == B) && (((ky >> 12) & 1023u) == B2);
                unsigned long long m2 = __ballot(e2);
                if (m2) {
                    unsigned int cnt = (unsigned)__popcll(m2);
                    unsigned int base;
                    if (lane == 0) base = atomicAdd(&out_cd2, cnt);
                    base = __shfl(base, 0, 64);
                    if (e2) {
                        unsigned int idx = base +
                            (unsigned)__popcll(m2 & ((1ull << lane) - 1ull));
                        cand2[idx] = ky;
                    }
                }
            }
            __syncthreads();                                    // B8
            // tiny rank-count: gt=#cand2>y, ge=#cand2>=y (uint4 broadcast;
            // zero pads never raise gt; participants have y>0)
            if (tid < (int)cd2) {
                unsigned int y = cand2[tid];
                unsigned int gt = 0u, ge = 0u;
                const uint4* c4 = (const uint4*)cand2;
                const int nq = (int)((cd2 + 3u) >> 2);
                for (int j = 0; j < nq; ++j) {
                    uint4 q = c4[j];
                    gt += (unsigned)(q.x > y) + (unsigned)(q.y > y)
                        + (unsigned)(q.z > y) + (unsigned)(q.w > y);
                    ge += (unsigned)(q.x >= y) + (unsigned)(q.y >= y)
                        + (unsigned)(q.z >= y) + (unsigned)(q.w >= y);
                }
                if (gt < kkv2 && ge >= kkv2) { sh_T = y; sh_g2 = gt; }
            }
            __syncthreads();                                    // B9
            Tkey  = sh_T;
            n_tie = kkv2 - sh_g2;
        } else {
            // ===== FALLBACK (massive ties): radix passes on bits 11..0 =====
            unsigned int prefix = (B << 22) | (B2 << 12);
            unsigned int pmask  = 0xFFFFF000u;
            unsigned int kkvf   = kkv2;
            const int      shifts2[2] = {2, 0};
            const unsigned nbv2[2]    = {1024u, 4u};
            for (int pass = 0; pass < 2; ++pass) {
                const int shift      = shifts2[pass];
                const unsigned nb    = nbv2[pass];
                const unsigned dmask = nb - 1u;
                if (tid < (int)nb) hist[tid] = 0u;
                __syncthreads();
                #pragma unroll
                for (int t = 0; t < EPT; ++t) {
                    unsigned int ky = keys[t];
                    if ((ky & pmask) == prefix)
                        atomicAdd(&hist[(ky >> shift) & dmask], 1u);
                }
                __syncthreads();
                unsigned int cc = (tid < (int)nb) ? hist[tid] : 0u;
                suffix_pick(cc, kkvf, tid, lane, wv,
                            wtot, &bc_digit, &bc_kk, &bc_cd);
                unsigned int newpref = prefix | (bc_digit << shift);
                if (pass < 1 && bc_kk == bc_cd && newpref != 0u) {
                    prefix = newpref - 1u;   // whole bin: T below bin, no ties
                    kkvf = 0u;
                    break;
                }
                prefix = newpref;
                kkvf = bc_kk;
                pmask |= dmask << shift;
            }
            Tkey  = prefix;
            n_tie = kkvf;
        }
    }

    // ---- wave-local compaction of selected keys (no atomics, no barrier) ---
    // hist is dead (pass-0 / fallback both consumed behind barriers).
    float* wbuf = (float*)&hist[(unsigned)wv << 9];      // 512 slots per wave
    unsigned int cnt = 0u;
    #pragma unroll
    for (int t = 0; t < EPT; ++t) {
        unsigned int ky = keys[t];
        bool s = ky > Tkey;
        unsigned long long m = __ballot(s);
        if (s) {
            unsigned int idx = cnt +
                (unsigned)__popcll(m & ((1ull << lane) - 1ull));
            wbuf[idx] = decode_key(ky);
        }
        cnt += (unsigned)__popcll(m);
    }

    // -------- bce partial sum: this wave's selected cols x block's rows -----
    const int rpg   = (rows_pb + 1) >> 1;
    const int rbase = blockIdx.x * rows_pb;
    int lim0 = rows_pb - 0 * rpg;  if (lim0 > rpg) lim0 = rpg;
    int lim1 = rows_pb - rpg;      if (lim1 > rpg) lim1 = rpg;
    {   // clip to n_pos
        int a0 = n_pos - rbase;           if (a0 < 0) a0 = 0;
        int a1 = n_pos - rbase - rpg;     if (a1 < 0) a1 = 0;
        if (lim0 > a0) lim0 = a0;
        if (lim1 > a1) lim1 = a1;
        if (lim1 < 0)  lim1 = 0;
    }
    float acc = 0.0f;
    const unsigned int total = cnt << 1;            // (col, row-half) pairs
    if (pos_in_lds) {
        for (unsigned int j = lane; j < total; j += 64) {
            float tv = wbuf[j >> 1];
            int h = (int)(j & 1u);
            const float* sp = &s_pos[h * rpg];
            int lim = h ? lim1 : lim0;
            for (int r = 0; r < lim; ++r) {
                float b = __logf(1.0f + __expf(tv - sp[r]));
                b = fminf(fmaxf(b, BCE_LO), BCE_HI);
                acc += b;
            }
        }
    } else {
        for (unsigned int j = lane; j < total; j += 64) {
            float tv = wbuf[j >> 1];
            int h = (int)(j & 1u);
            const float* gp = &pos[rbase + h * rpg];
            int lim = h ? lim1 : lim0;
            for (int r = 0; r < lim; ++r) {
                float b = __logf(1.0f + __expf(tv - gp[r]));
                b = fminf(fmaxf(b, BCE_LO), BCE_HI);
                acc += b;
            }
        }
    }
    // tie term: n_tie copies of decode(Tkey) against each row
    if (n_tie && tid < rows_pb && (rbase + tid) < n_pos) {
        float tvT = decode_key(Tkey);
        float pv  = pos_in_lds ? s_pos[tid] : pos[rbase + tid];
        float b = __logf(1.0f + __expf(tvT - pv));
        b = fminf(fmaxf(b, BCE_LO), BCE_HI);
        acc += (float)n_tie * b;
    }
    {   // DPP wave reduce (lane 63 of the prefix = wave sum), no LDS shfls
        float ap = wave_iprefix_f32(acc);
        if (lane == 63) s_red[wv] = ap;
    }
    __syncthreads();                                            // B10
    if (tid == 0) {
        float t = 0.0f;
        #pragma unroll
        for (int w = 0; w < BT / 64; ++w) t += s_red[w];
        __hip_atomic_store(&partials[blockIdx.x], t,
                           __ATOMIC_RELAXED, __HIP_MEMORY_SCOPE_AGENT);
        __hip_atomic_store(&done[blockIdx.x], 1u,
                           __ATOMIC_RELEASE, __HIP_MEMORY_SCOPE_AGENT);
    }

    // ---------------- block 0: gather the 256 partials ----------------------
    if (blockIdx.x == 0) {
        float a = 0.0f;
        if (tid < GRID) {
            while (__hip_atomic_load(&done[tid], __ATOMIC_RELAXED,
                                     __HIP_MEMORY_SCOPE_AGENT) != 1u)
                __builtin_amdgcn_s_sleep(1);
            __builtin_amdgcn_fence(__ATOMIC_ACQUIRE, "agent");
            a = __hip_atomic_load(&partials[tid], __ATOMIC_RELAXED,
                                  __HIP_MEMORY_SCOPE_AGENT);
        }
        float ap = wave_iprefix_f32(a);
        if (lane == 63) s_red[wv] = ap;
        __syncthreads();
        if (tid == 0) {
            float t = 0.0f;
            #pragma unroll
            for (int w = 0; w < BT / 64; ++w) t += s_red[w];
            out[0] = t * inv_denom;
        }
    }
}

extern "C" void kernel_launch(void* const* d_in, const int* in_sizes, int n_in,
                              void* d_out, int out_size, void* d_ws, size_t ws_size,
                              hipStream_t stream) {
    const float* neg = (const float*)d_in[0];   // score_neg, 16384
    const float* pos = (const float*)d_in[1];   // score_pos, 8192
    const int n_neg = in_sizes[0];
    const int n_pos = in_sizes[1];
    float* out = (float*)d_out;
    float* ws  = (float*)d_ws;

    int k = TOPK; if (k > n_neg) k = n_neg;
    float*        partials = ws;                             // [0, GRID)
    unsigned int* done     = (unsigned int*)(ws + GRID);     // [GRID, 2*GRID)

    const float inv_denom = (float)(1.0 / ((double)n_pos * (double)n_neg));
    pauc_fused_kernel<<<GRID, BT, 0, stream>>>(
        neg, n_neg, pos, n_pos, out, inv_denom, k, partials, done);
}